// Round 11
// baseline (203.565 us; speedup 1.0000x reference)
//
#include <hip/hip_runtime.h>
#include <stdint.h>
#include <math.h>

#define SEQ 2048
#define NH 16
#define DM 1024

typedef __bf16 bf16x8 __attribute__((ext_vector_type(8)));
typedef __bf16 bf16x2 __attribute__((ext_vector_type(2)));
typedef short s16x4 __attribute__((ext_vector_type(4)));
typedef short s16x8 __attribute__((ext_vector_type(8)));
typedef float f32x4 __attribute__((ext_vector_type(4)));
typedef float f32x2 __attribute__((ext_vector_type(2)));

#define ASM_VMCNT0  asm volatile("s_waitcnt vmcnt(0)" ::: "memory")
#define ASM_LGKM0   asm volatile("s_waitcnt lgkmcnt(0)" ::: "memory")
#define ASM_BARRIER asm volatile("s_barrier" ::: "memory")

__device__ __forceinline__ unsigned short f2bf(float f) {
  union { float f; unsigned u; } v; v.f = f;
  unsigned r = v.u + 0x7fffu + ((v.u >> 16) & 1u);
  return (unsigned short)(r >> 16);
}
__device__ __forceinline__ unsigned pk2(float a, float b) {
  f32x2 v = {a, b};
  bf16x2 r = __builtin_convertvector(v, bf16x2);  // v_cvt_pk_bf16_f32
  union { bf16x2 h; unsigned u; } c; c.h = r;
  return c.u;
}
__device__ __forceinline__ void load_lds16(const void* g, void* l) {
  __builtin_amdgcn_global_load_lds((__attribute__((address_space(1))) void*)g,
                                   (__attribute__((address_space(3))) void*)l,
                                   16, 0, 0);
}

// ---------------------------------------------------------------------------
// fp32 -> bf16 conversion: x (4M) + wq/wk/wv/wo (1M each) into ws.
// ---------------------------------------------------------------------------
__global__ void cvt_all(const float* __restrict__ x, const float* __restrict__ wq,
                        const float* __restrict__ wk, const float* __restrict__ wv,
                        const float* __restrict__ wo, unsigned short* __restrict__ ws) {
  const int i = blockIdx.x * blockDim.x + threadIdx.x;
  const int off = i * 4;
  const float* src;
  unsigned short* dst;
  if (off < 4194304) {
    src = x + off;  dst = ws + off;
  } else {
    const int r = off - 4194304;
    const int w = r >> 20, o = r & 1048575;
    const float* tabs[4] = {wq, wk, wv, wo};
    src = tabs[w] + o;  dst = ws + 4194304 + (w << 20) + o;
  }
  const float4 v = *(const float4*)src;
  uint2 u;
  u.x = pk2(v.x, v.y);
  u.y = pk2(v.z, v.w);
  *(uint2*)dst = u;
}

// ---------------------------------------------------------------------------
// Fused QKV projection: C = x (4096x1024) @ W3^T (W3 = [wq;wk;wv], 3072x1024).
// 128x128 tiles, grid (24,32) = 768 blocks; 3 blocks/CU.
// V epilogue writes the key dim PERMUTED within each 64-block (r20 layout):
//   key = nb*16 + qv*4 + j -> g = (nb>>1)*32 + qv*8 + (nb&1)*4 + j
// so flash wave kw reads its 4 PV A-frag chunks as 64 CONTIGUOUS bytes per
// V row: chunk for (quad q) at short-pos kw*32 + q*8 (verified both ways:
// s=37 -> g=41 -> (kw=1,q=1,off=1) -> key 37; s=53 -> g=45 -> vhi r=1 -> 53).
// ---------------------------------------------------------------------------
__launch_bounds__(256, 3)
__global__ void gemm_qkv(const unsigned short* __restrict__ X,
                         const unsigned short* __restrict__ W3,
                         unsigned short* __restrict__ Qr,
                         unsigned short* __restrict__ Kr,
                         unsigned short* __restrict__ Vt,
                         const int* __restrict__ tp) {
  __shared__ __align__(16) char smem[32768];

  const int t = threadIdx.x;
  const int lane = t & 63, wave = t >> 6;
  const int quad = lane >> 4, l16 = lane & 15;
  const int m0 = blockIdx.y * 128, n0 = blockIdx.x * 128;
  const int wm = (wave >> 1) * 64, wn = (wave & 1) * 64;

  f32x4 acc[4][4];
#pragma unroll
  for (int i = 0; i < 4; i++)
#pragma unroll
    for (int j = 0; j < 4; j++) { acc[i][j][0]=0.f; acc[i][j][1]=0.f; acc[i][j][2]=0.f; acc[i][j][3]=0.f; }

  const int rr = t >> 2;
  const int cc = (t & 3) * 8;

#define QKV_STAGE(bufidx, k0_) do {                                               \
    char* a_ = smem + (bufidx) * 8192;                                            \
    char* b_ = smem + 16384 + (bufidx) * 8192;                                    \
    _Pragma("unroll")                                                             \
    for (int i_ = 0; i_ < 2; i_++) {                                              \
      load_lds16(X  + (uint64_t)(m0 + i_ * 64 + rr) * 1024 + (k0_) + cc,          \
                 a_ + i_ * 4096 + wave * 1024);                                   \
      load_lds16(W3 + (uint64_t)(n0 + i_ * 64 + rr) * 1024 + (k0_) + cc,          \
                 b_ + i_ * 4096 + wave * 1024);                                   \
    }                                                                             \
  } while (0)

  QKV_STAGE(0, 0);

  for (int k0 = 0; k0 < 1024; k0 += 32) {
    const int buf = (k0 >> 5) & 1;
    ASM_VMCNT0;
    ASM_BARRIER;
    if (k0 + 32 < 1024) QKV_STAGE(buf ^ 1, k0 + 32);
    char* As = smem + buf * 8192;
    char* Bs = smem + 16384 + buf * 8192;

    bf16x8 af[4], bfr[4];
#pragma unroll
    for (int i = 0; i < 4; i++) {
      af[i]  = *(const bf16x8*)(As + (wm + i * 16 + l16) * 64 + quad * 16);
      bfr[i] = *(const bf16x8*)(Bs + (wn + i * 16 + l16) * 64 + quad * 16);
    }
#pragma unroll
    for (int i = 0; i < 4; i++)
#pragma unroll
      for (int j = 0; j < 4; j++)
        acc[i][j] = __builtin_amdgcn_mfma_f32_16x16x32_bf16(af[i], bfr[j], acc[i][j], 0, 0, 0);
  }
#undef QKV_STAGE

  if (n0 < 2048) {
    unsigned short* dst = (n0 < 1024) ? Qr : Kr;
    float fr[4]; int dd[4], hh[4];
#pragma unroll
    for (int j = 0; j < 4; j++) {
      const int n = n0 + wn + j * 16 + l16;
      dd[j] = n & 63;
      hh[j] = (n & 1023) >> 6;
      fr[j] = __builtin_amdgcn_exp2f(-0.20762050594f * (float)(dd[j] & ~1)) * 0.15915494309f;
    }
    const float sgnodd = (l16 & 1) ? 1.f : -1.f;
#pragma unroll
    for (int i = 0; i < 4; i++) {
#pragma unroll
      for (int r = 0; r < 4; r++) {
        const int m = m0 + wm + i * 16 + quad * 4 + r;
        const int s = m & 2047, b = m >> 11;
        const float posf = (float)tp[m];
#pragma unroll
        for (int j = 0; j < 4; j++) {
          const float v = acc[i][j][r];
          const float p = __shfl_xor(v, 1);
          float rev = posf * fr[j];
          rev -= floorf(rev);
          float sn, cs;
          asm("v_sin_f32 %0, %1" : "=v"(sn) : "v"(rev));
          asm("v_cos_f32 %0, %1" : "=v"(cs) : "v"(rev));
          const float rv = fmaf(v, cs, p * sn * sgnodd);
          dst[((uint64_t)((b * NH + hh[j]) * SEQ + s)) * 64 + dd[j]] = f2bf(rv);
        }
      }
    }
  } else {
    // V -> Vt (b,h,d,s_permuted r20): 4 consecutive s (=j) share (qv, nv).
#pragma unroll
    for (int i = 0; i < 4; i++) {
      const int m = m0 + wm + i * 16 + quad * 4;
      const int s = m & 2047, b = m >> 11;
      const int sl = s & 63;
      const int qv = (sl >> 2) & 3, nv = sl >> 4;
      const int g = (s & ~63) + (nv >> 1) * 32 + qv * 8 + (nv & 1) * 4;
#pragma unroll
      for (int j = 0; j < 4; j++) {
        const int n = n0 - 2048 + wn + j * 16 + l16;
        const int h = n >> 6, d = n & 63;
        uint2 w;
        w.x = pk2(acc[i][j][0], acc[i][j][1]);
        w.y = pk2(acc[i][j][2], acc[i][j][3]);
        *(uint2*)(Vt + ((uint64_t)((b * NH + h) * 64 + d)) * SEQ + g) = w;
      }
    }
  }
}

// ---------------------------------------------------------------------------
// Output projection: C = At (4096x1024) @ wo^T, fp32 out. 128x128 tiles,
// grid (8,32) = 256 blocks (1/CU), XCD-GROUPED remap (R7) + 512 threads /
// 8 waves (R9: 2 waves/SIMD, small win, kept).
// ---------------------------------------------------------------------------
__launch_bounds__(512, 2)
__global__ void gemm_ao(const unsigned short* __restrict__ A,
                        const unsigned short* __restrict__ B,
                        float* __restrict__ C) {
  __shared__ __align__(16) char smem[32768];

  const int t = threadIdx.x;
  const int lane = t & 63, wave = t >> 6;       // wave = 0..7
  const int quad = lane >> 4, l16 = lane & 15;
  const int id = blockIdx.y * 8 + blockIdx.x;   // linear dispatch id, 0..255
  const int k = id & 7;                         // XCD (1 block/CU round-robin)
  const int tt = id >> 3;                       // 0..31
  const int m0 = (k * 4 + (tt & 3)) * 128;      // XCD k: m-strips 4k..4k+3
  const int n0 = (tt >> 2) * 128;               // all 8 n-strips
  const int wm = (wave >> 2) * 64;              // 2 m-groups
  const int wn = (wave & 3) * 32;               // 4 n-groups

  f32x4 acc[4][2];
#pragma unroll
  for (int i = 0; i < 4; i++)
#pragma unroll
    for (int j = 0; j < 2; j++) { acc[i][j][0]=0.f; acc[i][j][1]=0.f; acc[i][j][2]=0.f; acc[i][j][3]=0.f; }

  const int rr = t >> 2;          // 0..127: full 128-row tile in one call
  const int cc = (t & 3) * 8;

#define AO_STAGE(bufidx, k0_) do {                                               \
    char* a_ = smem + (bufidx) * 8192;                                            \
    char* b_ = smem + 16384 + (bufidx) * 8192;                                    \
    load_lds16(A + (uint64_t)(m0 + rr) * 1024 + (k0_) + cc, a_ + wave * 1024);    \
    load_lds16(B + (uint64_t)(n0 + rr) * 1024 + (k0_) + cc, b_ + wave * 1024);    \
  } while (0)

  AO_STAGE(0, 0);

  for (int k0 = 0; k0 < 1024; k0 += 32) {
    const int buf = (k0 >> 5) & 1;
    ASM_VMCNT0;
    ASM_BARRIER;
    if (k0 + 32 < 1024) AO_STAGE(buf ^ 1, k0 + 32);
    char* As = smem + buf * 8192;
    char* Bs = smem + 16384 + buf * 8192;

    bf16x8 af[4], bfr[2];
#pragma unroll
    for (int i = 0; i < 4; i++)
      af[i]  = *(const bf16x8*)(As + (wm + i * 16 + l16) * 64 + quad * 16);
#pragma unroll
    for (int j = 0; j < 2; j++)
      bfr[j] = *(const bf16x8*)(Bs + (wn + j * 16 + l16) * 64 + quad * 16);
#pragma unroll
    for (int i = 0; i < 4; i++)
#pragma unroll
      for (int j = 0; j < 2; j++)
        acc[i][j] = __builtin_amdgcn_mfma_f32_16x16x32_bf16(af[i], bfr[j], acc[i][j], 0, 0, 0);
  }
#undef AO_STAGE

#pragma unroll
  for (int i = 0; i < 4; i++)
#pragma unroll
    for (int j = 0; j < 2; j++)
#pragma unroll
      for (int r = 0; r < 4; r++) {
        const int m = m0 + wm + i * 16 + quad * 4 + r;
        const int n = n0 + wn + j * 16 + l16;
        C[(uint64_t)m * DM + n] = acc[i][j][r];
      }
}

// ---------------------------------------------------------------------------
// Flash attention r20: NO K/V STAGING -- fragments read directly from L2.
// R10's win proved redundant reads of L2-resident data were the cost; the
// staging pipeline itself (vmcnt0 drain + barrier lockstep + LDS writes +
// 2.13M bank conflicts) is the rest. Per-XCD working set = 4 bh-planes x
// (K 256KB + V 256KB + Q 256KB) = 3MB <= 4MB L2 (u%8 == bh%8 keeps a bh's
// 32 blocks on one XCD). Guide common-mistake #7: don't LDS-stage L2-fit
// data (m169: +26%). Reads: kfr = 16B/lane, 4 quads cover 64B contiguous
// per K row (full line util); vv reads 64 contiguous B per V row via the
// r20 Vt permutation. All barriers/vmcnt/swizzle deleted; 16 waves/CU run
// fully independent. LDS (17KB) only for the final cross-kw reduction.
// L2-BW floor: 66 units/CU x 32KB = 2.1MB/CU ~ 14.6us.
// ---------------------------------------------------------------------------
__launch_bounds__(256, 4)
__global__ void flash_attn(const unsigned short* __restrict__ Q,
                           const unsigned short* __restrict__ K,
                           const unsigned short* __restrict__ Vt,
                           unsigned short* __restrict__ Oa) {
  __shared__ __align__(16) char smem[16640];   // final reduction only

  const int t = threadIdx.x;
  const int lane = t & 63, wid = t >> 6;     // wid = 0..3
  const int quad = lane >> 4, l16 = lane & 15;
  const int kw = wid & 1;                    // key-half owned by this wave
  const int qw = wid >> 1;                   // q-half owned by this wave
  const int u = blockIdx.x;
  const int m = u >> 5;                      // 0..31
  const int tq = (m < 16) ? (31 - m) : (m - 16);  // symmetric: per-CU sum 66
  const int bh = u & 31;
  const uint64_t base = (uint64_t)bh * (SEQ * 64);
  const int qb = tq * 64;
  const int ng = tq + 1;                     // K-tiles for this Q-tile
  const int b = bh >> 4, h = bh & 15;
  const int qlo = qb + qw * 32;              // wave's q range [qlo, qlo+32)

  // Q B-fragments for both 16-q subgroups (n=q=l16, k=d=kk*32+quad*8+j)
  bf16x8 qf[2][2];
  {
    const unsigned short* qp0 = Q + base + (uint64_t)(qlo + l16) * 64 + quad * 8;
    qf[0][0] = *(const bf16x8*)qp0;  qf[0][1] = *(const bf16x8*)(qp0 + 32);
    const unsigned short* qp1 = Q + base + (uint64_t)(qlo + 16 + l16) * 64 + quad * 8;
    qf[1][0] = *(const bf16x8*)qp1;  qf[1][1] = *(const bf16x8*)(qp1 + 32);
  }

  f32x4 o[2][4];                             // [qg][db], partial over wave's keys
#pragma unroll
  for (int qg = 0; qg < 2; qg++)
#pragma unroll
    for (int db = 0; db < 4; db++) { o[qg][db][0]=0.f; o[qg][db][1]=0.f; o[qg][db][2]=0.f; o[qg][db][3]=0.f; }
  float lI0 = 0.f, lI1 = 0.f;                // per-qg l partials

  const float c1 = 0.18033688011f;  // log2(e)/8

  for (int it = 0; it < ng; it++) {
    const int kb = it * 64;

    // wave's valid 16-key groups among {2kw, 2kw+1} relative to kb
    int nv = ((qlo + 31 - kb) >> 4) + 1 - 2 * kw;
    nv = nv > 2 ? 2 : (nv < 0 ? 0 : nv);
    const bool diag = (kb + kw * 32 + 31) > qlo;   // wave-uniform

    if (nv > 0) {
      // S^T = K Q^T : key = kb + (2kw+nbp)*16 + quad*4 + r, q (per qg) = l16
      // kfr direct from global: lanes of a (l16,quad) group cover 64B/row.
      f32x4 sf0[2], sf1[2];    // [nbp] for qg=0 / qg=1
      float ls0 = 0.f, ls1 = 0.f;
#pragma unroll
      for (int nbp = 0; nbp < 2; nbp++) {
        if (nbp < nv) {
          f32x4 s0; s0[0]=0.f; s0[1]=0.f; s0[2]=0.f; s0[3]=0.f;
          f32x4 s1; s1[0]=0.f; s1[1]=0.f; s1[2]=0.f; s1[3]=0.f;
#pragma unroll
          for (int kk = 0; kk < 2; kk++) {
            bf16x8 kfr = *(const bf16x8*)(K + base +
                (uint64_t)(kb + (2 * kw + nbp) * 16 + l16) * 64 + kk * 32 + quad * 8);
            s0 = __builtin_amdgcn_mfma_f32_16x16x32_bf16(kfr, qf[0][kk], s0, 0, 0, 0);
            s1 = __builtin_amdgcn_mfma_f32_16x16x32_bf16(kfr, qf[1][kk], s1, 0, 0, 0);
          }
          if (diag) {
#pragma unroll
            for (int r = 0; r < 4; r++) {
              const int key = kb + (2 * kw + nbp) * 16 + quad * 4 + r;
              const float p0 = (key <= qlo + l16)      ? __builtin_amdgcn_exp2f(s0[r] * c1) : 0.f;
              const float p1 = (key <= qlo + 16 + l16) ? __builtin_amdgcn_exp2f(s1[r] * c1) : 0.f;
              sf0[nbp][r] = p0;  ls0 += p0;
              sf1[nbp][r] = p1;  ls1 += p1;
            }
          } else {
#pragma unroll
            for (int r = 0; r < 4; r++) {
              const float p0 = __builtin_amdgcn_exp2f(s0[r] * c1);
              const float p1 = __builtin_amdgcn_exp2f(s1[r] * c1);
              sf0[nbp][r] = p0;  ls0 += p0;
              sf1[nbp][r] = p1;  ls1 += p1;
            }
          }
        }
      }
      lI0 += ls0;  lI1 += ls1;

      // PV: V A-frag direct from global (r20 Vt layout): wave kw, quad q
      // reads 16B at short-pos kb + kw*32 + q*8 of row d = db*16+l16.
      union { uint2 u; s16x4 h; } a0, b0, a1, b1;
      a0.u.x = pk2(sf0[0][0], sf0[0][1]);  a0.u.y = pk2(sf0[0][2], sf0[0][3]);
      b0.u.x = pk2(sf1[0][0], sf1[0][1]);  b0.u.y = pk2(sf1[0][2], sf1[0][3]);
      const bool hi = (nv > 1);
      if (hi) {
        a1.u.x = pk2(sf0[1][0], sf0[1][1]);  a1.u.y = pk2(sf0[1][2], sf0[1][3]);
        b1.u.x = pk2(sf1[1][0], sf1[1][1]);  b1.u.y = pk2(sf1[1][2], sf1[1][3]);
      }
#pragma unroll
      for (int db = 0; db < 4; db++) {
        s16x8 vv = *(const s16x8*)(Vt + base +
            (uint64_t)(db * 16 + l16) * SEQ + kb + kw * 32 + quad * 8);
        s16x4 vlo = __builtin_shufflevector(vv, vv, 0, 1, 2, 3);
        o[0][db] = __builtin_amdgcn_mfma_f32_16x16x16bf16_1k(vlo, a0.h, o[0][db], 0, 0, 0);
        o[1][db] = __builtin_amdgcn_mfma_f32_16x16x16bf16_1k(vlo, b0.h, o[1][db], 0, 0, 0);
        if (hi) {
          s16x4 vhi = __builtin_shufflevector(vv, vv, 4, 5, 6, 7);
          o[0][db] = __builtin_amdgcn_mfma_f32_16x16x16bf16_1k(vhi, a1.h, o[0][db], 0, 0, 0);
          o[1][db] = __builtin_amdgcn_mfma_f32_16x16x16bf16_1k(vhi, b1.h, o[1][db], 0, 0, 0);
        }
      }
    }
  }

  // reduce l across quads (per qg): butterfly leaves full wave-partial in all lanes
  float lr0 = lI0;  lr0 += __shfl_xor(lr0, 16);  lr0 += __shfl_xor(lr0, 32);
  float lr1 = lI1;  lr1 += __shfl_xor(lr1, 16);  lr1 += __shfl_xor(lr1, 32);

  // cross-kw reduction: kw=1 dumps partials to LDS, kw=0 adds + finalizes.
  ASM_BARRIER;
  if (kw) {
    char* pbase = smem + qw * 8192;
#pragma unroll
    for (int qg = 0; qg < 2; qg++)
#pragma unroll
      for (int db = 0; db < 4; db++)
        *(f32x4*)(pbase + (qg * 4 + db) * 1024 + quad * 256 + l16 * 16) = o[qg][db];
    if (quad == 0) {
      *(float*)(smem + 16384 + qw * 128 + l16 * 4) = lr0;
      *(float*)(smem + 16384 + qw * 128 + 64 + l16 * 4) = lr1;
    }
  }
  ASM_LGKM0;
  ASM_BARRIER;
  if (!kw) {
    char* pbase = smem + qw * 8192;
#pragma unroll
    for (int qg = 0; qg < 2; qg++) {
      const float lpart = *(const float*)(smem + 16384 + qw * 128 + qg * 64 + l16 * 4);
      const float invl = 1.0f / ((qg ? lr1 : lr0) + lpart);
      const int qrow = qlo + qg * 16 + l16;
      unsigned short* orow = Oa + ((uint64_t)(b * SEQ + qrow)) * DM + h * 64 + quad * 4;
#pragma unroll
      for (int db = 0; db < 4; db++) {
        const f32x4 p = *(const f32x4*)(pbase + (qg * 4 + db) * 1024 + quad * 256 + l16 * 16);
        uint2 w;
        w.x = pk2((o[qg][db][0] + p[0]) * invl, (o[qg][db][1] + p[1]) * invl);
        w.y = pk2((o[qg][db][2] + p[2]) * invl, (o[qg][db][3] + p[3]) * invl);
        *(uint2*)(orow + db * 16) = w;
      }
    }
  }
}

extern "C" void kernel_launch(void* const* d_in, const int* in_sizes, int n_in,
                              void* d_out, int out_size, void* d_ws, size_t ws_size,
                              hipStream_t stream) {
  const float* x  = (const float*)d_in[0];
  const int* tp   = (const int*)d_in[1];
  const float* wq = (const float*)d_in[2];
  const float* wk = (const float*)d_in[3];
  const float* wv = (const float*)d_in[4];
  const float* wo = (const float*)d_in[5];
  float* out = (float*)d_out;

  unsigned short* ws = (unsigned short*)d_ws;
  unsigned short* xb  = ws;                   // (b,s,dm) bf16        8 MB
  unsigned short* w3b = ws + 4194304;         // [wq;wk;wv] 3072x1024 6 MB
  unsigned short* wob = ws + 7340032;         // 2 MB
  unsigned short* Qr  = ws + 8388608;         // (b,h,s,64)  8 MB
  unsigned short* Kr  = ws + 12582912;        // (b,h,s,64)  8 MB
  unsigned short* Vt  = ws + 16777216;        // (b,h,64,s-perm r20)  8 MB
  unsigned short* At  = ws + 20971520;        // (b,s,h*64)  8 MB

  cvt_all<<<8192, 256, 0, stream>>>(x, wq, wk, wv, wo, ws);
  gemm_qkv<<<dim3(24, 32), 256, 0, stream>>>(xb, w3b, Qr, Kr, Vt, tp);
  flash_attn<<<1024, 256, 0, stream>>>(Qr, Kr, Vt, At);
  gemm_ao<<<dim3(8, 32), 512, 0, stream>>>(At, wob, out);
}

// Round 12
// 180.318 us; speedup vs baseline: 1.1289x; 1.1289x over previous
//
#include <hip/hip_runtime.h>
#include <stdint.h>
#include <math.h>

#define SEQ 2048
#define NH 16
#define DM 1024

typedef __bf16 bf16x8 __attribute__((ext_vector_type(8)));
typedef __bf16 bf16x2 __attribute__((ext_vector_type(2)));
typedef short s16x4 __attribute__((ext_vector_type(4)));
typedef short s16x8 __attribute__((ext_vector_type(8)));
typedef float f32x4 __attribute__((ext_vector_type(4)));
typedef float f32x2 __attribute__((ext_vector_type(2)));

#define ASM_VMCNT0  asm volatile("s_waitcnt vmcnt(0)" ::: "memory")
#define ASM_LGKM0   asm volatile("s_waitcnt lgkmcnt(0)" ::: "memory")
#define ASM_BARRIER asm volatile("s_barrier" ::: "memory")

__device__ __forceinline__ unsigned short f2bf(float f) {
  union { float f; unsigned u; } v; v.f = f;
  unsigned r = v.u + 0x7fffu + ((v.u >> 16) & 1u);
  return (unsigned short)(r >> 16);
}
__device__ __forceinline__ unsigned pk2(float a, float b) {
  f32x2 v = {a, b};
  bf16x2 r = __builtin_convertvector(v, bf16x2);  // v_cvt_pk_bf16_f32
  union { bf16x2 h; unsigned u; } c; c.h = r;
  return c.u;
}
__device__ __forceinline__ void load_lds16(const void* g, void* l) {
  __builtin_amdgcn_global_load_lds((__attribute__((address_space(1))) void*)g,
                                   (__attribute__((address_space(3))) void*)l,
                                   16, 0, 0);
}

// ---------------------------------------------------------------------------
// fp32 -> bf16 conversion: x (4M) + wq/wk/wv/wo (1M each) into ws.
// ---------------------------------------------------------------------------
__global__ void cvt_all(const float* __restrict__ x, const float* __restrict__ wq,
                        const float* __restrict__ wk, const float* __restrict__ wv,
                        const float* __restrict__ wo, unsigned short* __restrict__ ws) {
  const int i = blockIdx.x * blockDim.x + threadIdx.x;
  const int off = i * 4;
  const float* src;
  unsigned short* dst;
  if (off < 4194304) {
    src = x + off;  dst = ws + off;
  } else {
    const int r = off - 4194304;
    const int w = r >> 20, o = r & 1048575;
    const float* tabs[4] = {wq, wk, wv, wo};
    src = tabs[w] + o;  dst = ws + 4194304 + (w << 20) + o;
  }
  const float4 v = *(const float4*)src;
  uint2 u;
  u.x = pk2(v.x, v.y);
  u.y = pk2(v.z, v.w);
  *(uint2*)dst = u;
}

// ---------------------------------------------------------------------------
// Fused QKV projection: C = x (4096x1024) @ W3^T (W3 = [wq;wk;wv], 3072x1024).
// 128x128 tiles, grid (24,32) = 768 blocks; 3 blocks/CU.
// V epilogue writes the key dim PERMUTED within each 64-block (r20 layout,
// correctness harness-verified in R11):
//   key = nb*16 + qv*4 + j -> g = (nb>>1)*32 + qv*8 + (nb&1)*4 + j
// so flash wave kw reads its PV A-frag pair as 16 CONTIGUOUS bytes per V row
// at short-pos kw*32 + quad*8.
// ---------------------------------------------------------------------------
__launch_bounds__(256, 3)
__global__ void gemm_qkv(const unsigned short* __restrict__ X,
                         const unsigned short* __restrict__ W3,
                         unsigned short* __restrict__ Qr,
                         unsigned short* __restrict__ Kr,
                         unsigned short* __restrict__ Vt,
                         const int* __restrict__ tp) {
  __shared__ __align__(16) char smem[32768];

  const int t = threadIdx.x;
  const int lane = t & 63, wave = t >> 6;
  const int quad = lane >> 4, l16 = lane & 15;
  const int m0 = blockIdx.y * 128, n0 = blockIdx.x * 128;
  const int wm = (wave >> 1) * 64, wn = (wave & 1) * 64;

  f32x4 acc[4][4];
#pragma unroll
  for (int i = 0; i < 4; i++)
#pragma unroll
    for (int j = 0; j < 4; j++) { acc[i][j][0]=0.f; acc[i][j][1]=0.f; acc[i][j][2]=0.f; acc[i][j][3]=0.f; }

  const int rr = t >> 2;
  const int cc = (t & 3) * 8;

#define QKV_STAGE(bufidx, k0_) do {                                               \
    char* a_ = smem + (bufidx) * 8192;                                            \
    char* b_ = smem + 16384 + (bufidx) * 8192;                                    \
    _Pragma("unroll")                                                             \
    for (int i_ = 0; i_ < 2; i_++) {                                              \
      load_lds16(X  + (uint64_t)(m0 + i_ * 64 + rr) * 1024 + (k0_) + cc,          \
                 a_ + i_ * 4096 + wave * 1024);                                   \
      load_lds16(W3 + (uint64_t)(n0 + i_ * 64 + rr) * 1024 + (k0_) + cc,          \
                 b_ + i_ * 4096 + wave * 1024);                                   \
    }                                                                             \
  } while (0)

  QKV_STAGE(0, 0);

  for (int k0 = 0; k0 < 1024; k0 += 32) {
    const int buf = (k0 >> 5) & 1;
    ASM_VMCNT0;
    ASM_BARRIER;
    if (k0 + 32 < 1024) QKV_STAGE(buf ^ 1, k0 + 32);
    char* As = smem + buf * 8192;
    char* Bs = smem + 16384 + buf * 8192;

    bf16x8 af[4], bfr[4];
#pragma unroll
    for (int i = 0; i < 4; i++) {
      af[i]  = *(const bf16x8*)(As + (wm + i * 16 + l16) * 64 + quad * 16);
      bfr[i] = *(const bf16x8*)(Bs + (wn + i * 16 + l16) * 64 + quad * 16);
    }
#pragma unroll
    for (int i = 0; i < 4; i++)
#pragma unroll
      for (int j = 0; j < 4; j++)
        acc[i][j] = __builtin_amdgcn_mfma_f32_16x16x32_bf16(af[i], bfr[j], acc[i][j], 0, 0, 0);
  }
#undef QKV_STAGE

  if (n0 < 2048) {
    unsigned short* dst = (n0 < 1024) ? Qr : Kr;
    float fr[4]; int dd[4], hh[4];
#pragma unroll
    for (int j = 0; j < 4; j++) {
      const int n = n0 + wn + j * 16 + l16;
      dd[j] = n & 63;
      hh[j] = (n & 1023) >> 6;
      fr[j] = __builtin_amdgcn_exp2f(-0.20762050594f * (float)(dd[j] & ~1)) * 0.15915494309f;
    }
    const float sgnodd = (l16 & 1) ? 1.f : -1.f;
#pragma unroll
    for (int i = 0; i < 4; i++) {
#pragma unroll
      for (int r = 0; r < 4; r++) {
        const int m = m0 + wm + i * 16 + quad * 4 + r;
        const int s = m & 2047, b = m >> 11;
        const float posf = (float)tp[m];
#pragma unroll
        for (int j = 0; j < 4; j++) {
          const float v = acc[i][j][r];
          const float p = __shfl_xor(v, 1);
          float rev = posf * fr[j];
          rev -= floorf(rev);
          float sn, cs;
          asm("v_sin_f32 %0, %1" : "=v"(sn) : "v"(rev));
          asm("v_cos_f32 %0, %1" : "=v"(cs) : "v"(rev));
          const float rv = fmaf(v, cs, p * sn * sgnodd);
          dst[((uint64_t)((b * NH + hh[j]) * SEQ + s)) * 64 + dd[j]] = f2bf(rv);
        }
      }
    }
  } else {
    // V -> Vt (b,h,d,s_permuted r20): 4 consecutive s (=j) share (qv, nv).
#pragma unroll
    for (int i = 0; i < 4; i++) {
      const int m = m0 + wm + i * 16 + quad * 4;
      const int s = m & 2047, b = m >> 11;
      const int sl = s & 63;
      const int qv = (sl >> 2) & 3, nv = sl >> 4;
      const int g = (s & ~63) + (nv >> 1) * 32 + qv * 8 + (nv & 1) * 4;
#pragma unroll
      for (int j = 0; j < 4; j++) {
        const int n = n0 - 2048 + wn + j * 16 + l16;
        const int h = n >> 6, d = n & 63;
        uint2 w;
        w.x = pk2(acc[i][j][0], acc[i][j][1]);
        w.y = pk2(acc[i][j][2], acc[i][j][3]);
        *(uint2*)(Vt + ((uint64_t)((b * NH + h) * 64 + d)) * SEQ + g) = w;
      }
    }
  }
}

// ---------------------------------------------------------------------------
// Output projection: C = At (4096x1024) @ wo^T, fp32 out. 128x128 tiles,
// grid (8,32) = 256 blocks (1/CU), XCD-GROUPED remap (R7) + 512 threads /
// 8 waves (R9: 2 waves/SIMD, kept).
// ---------------------------------------------------------------------------
__launch_bounds__(512, 2)
__global__ void gemm_ao(const unsigned short* __restrict__ A,
                        const unsigned short* __restrict__ B,
                        float* __restrict__ C) {
  __shared__ __align__(16) char smem[32768];

  const int t = threadIdx.x;
  const int lane = t & 63, wave = t >> 6;       // wave = 0..7
  const int quad = lane >> 4, l16 = lane & 15;
  const int id = blockIdx.y * 8 + blockIdx.x;   // linear dispatch id, 0..255
  const int k = id & 7;                         // XCD (1 block/CU round-robin)
  const int tt = id >> 3;                       // 0..31
  const int m0 = (k * 4 + (tt & 3)) * 128;      // XCD k: m-strips 4k..4k+3
  const int n0 = (tt >> 2) * 128;               // all 8 n-strips
  const int wm = (wave >> 2) * 64;              // 2 m-groups
  const int wn = (wave & 3) * 32;               // 4 n-groups

  f32x4 acc[4][2];
#pragma unroll
  for (int i = 0; i < 4; i++)
#pragma unroll
    for (int j = 0; j < 2; j++) { acc[i][j][0]=0.f; acc[i][j][1]=0.f; acc[i][j][2]=0.f; acc[i][j][3]=0.f; }

  const int rr = t >> 2;          // 0..127: full 128-row tile in one call
  const int cc = (t & 3) * 8;

#define AO_STAGE(bufidx, k0_) do {                                               \
    char* a_ = smem + (bufidx) * 8192;                                            \
    char* b_ = smem + 16384 + (bufidx) * 8192;                                    \
    load_lds16(A + (uint64_t)(m0 + rr) * 1024 + (k0_) + cc, a_ + wave * 1024);    \
    load_lds16(B + (uint64_t)(n0 + rr) * 1024 + (k0_) + cc, b_ + wave * 1024);    \
  } while (0)

  AO_STAGE(0, 0);

  for (int k0 = 0; k0 < 1024; k0 += 32) {
    const int buf = (k0 >> 5) & 1;
    ASM_VMCNT0;
    ASM_BARRIER;
    if (k0 + 32 < 1024) AO_STAGE(buf ^ 1, k0 + 32);
    char* As = smem + buf * 8192;
    char* Bs = smem + 16384 + buf * 8192;

    bf16x8 af[4], bfr[2];
#pragma unroll
    for (int i = 0; i < 4; i++)
      af[i]  = *(const bf16x8*)(As + (wm + i * 16 + l16) * 64 + quad * 16);
#pragma unroll
    for (int j = 0; j < 2; j++)
      bfr[j] = *(const bf16x8*)(Bs + (wn + j * 16 + l16) * 64 + quad * 16);
#pragma unroll
    for (int i = 0; i < 4; i++)
#pragma unroll
      for (int j = 0; j < 2; j++)
        acc[i][j] = __builtin_amdgcn_mfma_f32_16x16x32_bf16(af[i], bfr[j], acc[i][j], 0, 0, 0);
  }
#undef AO_STAGE

#pragma unroll
  for (int i = 0; i < 4; i++)
#pragma unroll
    for (int j = 0; j < 2; j++)
#pragma unroll
      for (int r = 0; r < 4; r++) {
        const int m = m0 + wm + i * 16 + quad * 4 + r;
        const int n = n0 + wn + j * 16 + l16;
        C[(uint64_t)m * DM + n] = acc[i][j][r];
      }
}

// ---------------------------------------------------------------------------
// Flash attention r21: HYBRID -- K staged in LDS (r19 path), V direct from L2.
// R11 post-mortem: removing ALL staging exposed ~200cy L2 latency on the K
// load -> first MFMA chain (flash 38->72us, conflicts 0, MfmaUtil 13) --
// staging's value is PREFETCH DISTANCE, not LDS bandwidth. K must stay
// staged (feeds the chain head). V is consumed ~600-800cy after iteration
// start: a V load issued right after the barrier hides its own L2 latency
// under QK^T + softmax. So: r19's swizzled K staging + vmcnt/barrier pipeline
// unchanged; V read direct via the r20 contiguous Vt layout (verified R11),
// issued EARLY into registers. Halves staging traffic, LDS writes and LDS
// reads; K-latency path untouched.
// ---------------------------------------------------------------------------
__launch_bounds__(256, 4)
__global__ void flash_attn(const unsigned short* __restrict__ Q,
                           const unsigned short* __restrict__ K,
                           const unsigned short* __restrict__ Vt,
                           unsigned short* __restrict__ Oa) {
  __shared__ __align__(16) char smem[16640];
  // K dbuf: 0 / 8192 (64 rows x 128B each); reduction reuses [0, 16640)

  const int t = threadIdx.x;
  const int lane = t & 63, wid = t >> 6;     // wid = 0..3
  const int quad = lane >> 4, l16 = lane & 15;
  const int kw = wid & 1;                    // key-half owned by this wave
  const int qw = wid >> 1;                   // q-half owned by this wave
  const int u = blockIdx.x;
  const int m = u >> 5;                      // 0..31
  const int tq = (m < 16) ? (31 - m) : (m - 16);  // symmetric: per-CU sum 66
  const int bh = u & 31;
  const uint64_t base = (uint64_t)bh * (SEQ * 64);
  const int qb = tq * 64;
  const int ng = tq + 1;                     // K-tiles for this Q-tile
  const int b = bh >> 4, h = bh & 15;
  const int qlo = qb + qw * 32;              // wave's q range [qlo, qlo+32)

  // Q B-fragments for both 16-q subgroups (n=q=l16, k=d=kk*32+quad*8+j)
  bf16x8 qf[2][2];
  {
    const unsigned short* qp0 = Q + base + (uint64_t)(qlo + l16) * 64 + quad * 8;
    qf[0][0] = *(const bf16x8*)qp0;  qf[0][1] = *(const bf16x8*)(qp0 + 32);
    const unsigned short* qp1 = Q + base + (uint64_t)(qlo + 16 + l16) * 64 + quad * 8;
    qf[1][0] = *(const bf16x8*)qp1;  qf[1][1] = *(const bf16x8*)(qp1 + 32);
  }

  f32x4 o[2][4];                             // [qg][db], partial over wave's keys
#pragma unroll
  for (int qg = 0; qg < 2; qg++)
#pragma unroll
    for (int db = 0; db < 4; db++) { o[qg][db][0]=0.f; o[qg][db][1]=0.f; o[qg][db][2]=0.f; o[qg][db][3]=0.f; }
  float lI0 = 0.f, lI1 = 0.f;                // per-qg l partials

  // K staging: 256 threads cover the 64-row x 128B K tile in 2 calls.
  // LDS chunk c at row r holds global 16B-chunk c ^ (r&7).
  const int sr8 = lane >> 3;
  const int sc = ((lane & 7) ^ sr8) * 8;     // shorts
  const int swz = (l16 & 7);

#define STAGE_K(bufidx, kb_) do {                                                 \
    _Pragma("unroll")                                                             \
    for (int i_ = 0; i_ < 2; i_++) {                                              \
      const int r_ = wid * 16 + i_ * 8 + sr8;                                     \
      load_lds16(K + base + (uint64_t)((kb_) + r_) * 64 + sc,                     \
                 smem + (bufidx) * 8192 + wid * 2048 + i_ * 1024);                \
    }                                                                             \
  } while (0)

  STAGE_K(0, 0);

  const float c1 = 0.18033688011f;  // log2(e)/8
  const unsigned short* vrow = Vt + base + kw * 32 + quad * 8;

  for (int it = 0; it < ng; it++) {
    const int kb = it * 64;
    const int buf = it & 1;
    ASM_VMCNT0;     // stage(it) K loads were issued a full iteration ago
    ASM_BARRIER;
    if (it + 1 < ng) STAGE_K(buf ^ 1, (it + 1) * 64);
    char* ks = smem + buf * 8192;

    // wave's valid 16-key groups among {2kw, 2kw+1} relative to kb
    int nv = ((qlo + 31 - kb) >> 4) + 1 - 2 * kw;
    nv = nv > 2 ? 2 : (nv < 0 ? 0 : nv);
    const bool diag = (kb + kw * 32 + 31) > qlo;   // wave-uniform

    if (nv > 0) {
      // ISSUE V LOADS EARLY: consumed after QK^T + softmax (~600-800 cy) --
      // L2 latency (~200 cy) hides under the compute between issue and use.
      s16x8 vv[4];
#pragma unroll
      for (int db = 0; db < 4; db++)
        vv[db] = *(const s16x8*)(vrow + (uint64_t)(db * 16 + l16) * SEQ + kb);

      // S^T = K Q^T : key = kb + (2kw+nbp)*16 + quad*4 + r, q (per qg) = l16
      f32x4 sf0[2], sf1[2];    // [nbp] for qg=0 / qg=1
      float ls0 = 0.f, ls1 = 0.f;
#pragma unroll
      for (int nbp = 0; nbp < 2; nbp++) {
        if (nbp < nv) {
          f32x4 s0; s0[0]=0.f; s0[1]=0.f; s0[2]=0.f; s0[3]=0.f;
          f32x4 s1; s1[0]=0.f; s1[1]=0.f; s1[2]=0.f; s1[3]=0.f;
#pragma unroll
          for (int kk = 0; kk < 2; kk++) {
            bf16x8 kfr = *(const bf16x8*)(ks + ((2 * kw + nbp) * 16 + l16) * 128 +
                                          (((kk * 4 + quad) ^ swz) * 16));
            s0 = __builtin_amdgcn_mfma_f32_16x16x32_bf16(kfr, qf[0][kk], s0, 0, 0, 0);
            s1 = __builtin_amdgcn_mfma_f32_16x16x32_bf16(kfr, qf[1][kk], s1, 0, 0, 0);
          }
          if (diag) {
#pragma unroll
            for (int r = 0; r < 4; r++) {
              const int key = kb + (2 * kw + nbp) * 16 + quad * 4 + r;
              const float p0 = (key <= qlo + l16)      ? __builtin_amdgcn_exp2f(s0[r] * c1) : 0.f;
              const float p1 = (key <= qlo + 16 + l16) ? __builtin_amdgcn_exp2f(s1[r] * c1) : 0.f;
              sf0[nbp][r] = p0;  ls0 += p0;
              sf1[nbp][r] = p1;  ls1 += p1;
            }
          } else {
#pragma unroll
            for (int r = 0; r < 4; r++) {
              const float p0 = __builtin_amdgcn_exp2f(s0[r] * c1);
              const float p1 = __builtin_amdgcn_exp2f(s1[r] * c1);
              sf0[nbp][r] = p0;  ls0 += p0;
              sf1[nbp][r] = p1;  ls1 += p1;
            }
          }
        }
      }
      lI0 += ls0;  lI1 += ls1;

      // PV: V A-frags from the early-issued registers.
      union { uint2 u; s16x4 h; } a0, b0, a1, b1;
      a0.u.x = pk2(sf0[0][0], sf0[0][1]);  a0.u.y = pk2(sf0[0][2], sf0[0][3]);
      b0.u.x = pk2(sf1[0][0], sf1[0][1]);  b0.u.y = pk2(sf1[0][2], sf1[0][3]);
      const bool hi = (nv > 1);
      if (hi) {
        a1.u.x = pk2(sf0[1][0], sf0[1][1]);  a1.u.y = pk2(sf0[1][2], sf0[1][3]);
        b1.u.x = pk2(sf1[1][0], sf1[1][1]);  b1.u.y = pk2(sf1[1][2], sf1[1][3]);
      }
#pragma unroll
      for (int db = 0; db < 4; db++) {
        s16x4 vlo = __builtin_shufflevector(vv[db], vv[db], 0, 1, 2, 3);
        o[0][db] = __builtin_amdgcn_mfma_f32_16x16x16bf16_1k(vlo, a0.h, o[0][db], 0, 0, 0);
        o[1][db] = __builtin_amdgcn_mfma_f32_16x16x16bf16_1k(vlo, b0.h, o[1][db], 0, 0, 0);
        if (hi) {
          s16x4 vhi = __builtin_shufflevector(vv[db], vv[db], 4, 5, 6, 7);
          o[0][db] = __builtin_amdgcn_mfma_f32_16x16x16bf16_1k(vhi, a1.h, o[0][db], 0, 0, 0);
          o[1][db] = __builtin_amdgcn_mfma_f32_16x16x16bf16_1k(vhi, b1.h, o[1][db], 0, 0, 0);
        }
      }
    }
  }
#undef STAGE_K

  // reduce l across quads (per qg): butterfly leaves full wave-partial in all lanes
  float lr0 = lI0;  lr0 += __shfl_xor(lr0, 16);  lr0 += __shfl_xor(lr0, 32);
  float lr1 = lI1;  lr1 += __shfl_xor(lr1, 16);  lr1 += __shfl_xor(lr1, 32);

  // cross-kw reduction: kw=1 dumps partials to LDS, kw=0 adds + finalizes.
  ASM_LGKM0;        // all my LDS reads retired before anyone overwrites smem
  ASM_BARRIER;
  if (kw) {
    char* pbase = smem + qw * 8192;
#pragma unroll
    for (int qg = 0; qg < 2; qg++)
#pragma unroll
      for (int db = 0; db < 4; db++)
        *(f32x4*)(pbase + (qg * 4 + db) * 1024 + quad * 256 + l16 * 16) = o[qg][db];
    if (quad == 0) {
      *(float*)(smem + 16384 + qw * 128 + l16 * 4) = lr0;
      *(float*)(smem + 16384 + qw * 128 + 64 + l16 * 4) = lr1;
    }
  }
  ASM_LGKM0;
  ASM_BARRIER;
  if (!kw) {
    char* pbase = smem + qw * 8192;
#pragma unroll
    for (int qg = 0; qg < 2; qg++) {
      const float lpart = *(const float*)(smem + 16384 + qw * 128 + qg * 64 + l16 * 4);
      const float invl = 1.0f / ((qg ? lr1 : lr0) + lpart);
      const int qrow = qlo + qg * 16 + l16;
      unsigned short* orow = Oa + ((uint64_t)(b * SEQ + qrow)) * DM + h * 64 + quad * 4;
#pragma unroll
      for (int db = 0; db < 4; db++) {
        const f32x4 p = *(const f32x4*)(pbase + (qg * 4 + db) * 1024 + quad * 256 + l16 * 16);
        uint2 w;
        w.x = pk2((o[qg][db][0] + p[0]) * invl, (o[qg][db][1] + p[1]) * invl);
        w.y = pk2((o[qg][db][2] + p[2]) * invl, (o[qg][db][3] + p[3]) * invl);
        *(uint2*)(orow + db * 16) = w;
      }
    }
  }
}

extern "C" void kernel_launch(void* const* d_in, const int* in_sizes, int n_in,
                              void* d_out, int out_size, void* d_ws, size_t ws_size,
                              hipStream_t stream) {
  const float* x  = (const float*)d_in[0];
  const int* tp   = (const int*)d_in[1];
  const float* wq = (const float*)d_in[2];
  const float* wk = (const float*)d_in[3];
  const float* wv = (const float*)d_in[4];
  const float* wo = (const float*)d_in[5];
  float* out = (float*)d_out;

  unsigned short* ws = (unsigned short*)d_ws;
  unsigned short* xb  = ws;                   // (b,s,dm) bf16        8 MB
  unsigned short* w3b = ws + 4194304;         // [wq;wk;wv] 3072x1024 6 MB
  unsigned short* wob = ws + 7340032;         // 2 MB
  unsigned short* Qr  = ws + 8388608;         // (b,h,s,64)  8 MB
  unsigned short* Kr  = ws + 12582912;        // (b,h,s,64)  8 MB
  unsigned short* Vt  = ws + 16777216;        // (b,h,64,s-perm r20)  8 MB
  unsigned short* At  = ws + 20971520;        // (b,s,h*64)  8 MB

  cvt_all<<<8192, 256, 0, stream>>>(x, wq, wk, wv, wo, ws);
  gemm_qkv<<<dim3(24, 32), 256, 0, stream>>>(xb, w3b, Qr, Kr, Vt, tp);
  flash_attn<<<1024, 256, 0, stream>>>(Qr, Kr, Vt, At);
  gemm_ao<<<dim3(8, 32), 512, 0, stream>>>(At, wob, out);
}

// Round 13
// 165.659 us; speedup vs baseline: 1.2288x; 1.0885x over previous
//
#include <hip/hip_runtime.h>
#include <stdint.h>
#include <math.h>

#define SEQ 2048
#define NH 16
#define DM 1024

typedef __bf16 bf16x8 __attribute__((ext_vector_type(8)));
typedef __bf16 bf16x2 __attribute__((ext_vector_type(2)));
typedef short s16x4 __attribute__((ext_vector_type(4)));
typedef short s16x8 __attribute__((ext_vector_type(8)));
typedef float f32x4 __attribute__((ext_vector_type(4)));
typedef float f32x2 __attribute__((ext_vector_type(2)));

#define ASM_VMCNT0  asm volatile("s_waitcnt vmcnt(0)" ::: "memory")
#define ASM_LGKM0   asm volatile("s_waitcnt lgkmcnt(0)" ::: "memory")
#define ASM_BARRIER asm volatile("s_barrier" ::: "memory")

__device__ __forceinline__ unsigned short f2bf(float f) {
  union { float f; unsigned u; } v; v.f = f;
  unsigned r = v.u + 0x7fffu + ((v.u >> 16) & 1u);
  return (unsigned short)(r >> 16);
}
__device__ __forceinline__ unsigned pk2(float a, float b) {
  f32x2 v = {a, b};
  bf16x2 r = __builtin_convertvector(v, bf16x2);  // v_cvt_pk_bf16_f32
  union { bf16x2 h; unsigned u; } c; c.h = r;
  return c.u;
}
__device__ __forceinline__ void load_lds16(const void* g, void* l) {
  __builtin_amdgcn_global_load_lds((__attribute__((address_space(1))) void*)g,
                                   (__attribute__((address_space(3))) void*)l,
                                   16, 0, 0);
}

// ---------------------------------------------------------------------------
// fp32 -> bf16 conversion: x (4M) + wq/wk/wv/wo (1M each) into ws.
// ---------------------------------------------------------------------------
__global__ void cvt_all(const float* __restrict__ x, const float* __restrict__ wq,
                        const float* __restrict__ wk, const float* __restrict__ wv,
                        const float* __restrict__ wo, unsigned short* __restrict__ ws) {
  const int i = blockIdx.x * blockDim.x + threadIdx.x;
  const int off = i * 4;
  const float* src;
  unsigned short* dst;
  if (off < 4194304) {
    src = x + off;  dst = ws + off;
  } else {
    const int r = off - 4194304;
    const int w = r >> 20, o = r & 1048575;
    const float* tabs[4] = {wq, wk, wv, wo};
    src = tabs[w] + o;  dst = ws + 4194304 + (w << 20) + o;
  }
  const float4 v = *(const float4*)src;
  uint2 u;
  u.x = pk2(v.x, v.y);
  u.y = pk2(v.z, v.w);
  *(uint2*)dst = u;
}

// ---------------------------------------------------------------------------
// Fused QKV projection: C = x (4096x1024) @ W3^T (W3 = [wq;wk;wv], 3072x1024).
// 128x128 tiles, grid (24,32) = 768 blocks; 3 blocks/CU.
// V epilogue writes the key dim PERMUTED within each 64-block (r19 layout):
//   key = nb*16 + quad*4 + j  ->  g = quad*16 + (nb>>1)*8 + (nb&1)*4 + j
// so flash PV A-fragments (4 keys/lane, 2 nb per 16B) are b128-loadable.
// ---------------------------------------------------------------------------
__launch_bounds__(256, 3)
__global__ void gemm_qkv(const unsigned short* __restrict__ X,
                         const unsigned short* __restrict__ W3,
                         unsigned short* __restrict__ Qr,
                         unsigned short* __restrict__ Kr,
                         unsigned short* __restrict__ Vt,
                         const int* __restrict__ tp) {
  __shared__ __align__(16) char smem[32768];

  const int t = threadIdx.x;
  const int lane = t & 63, wave = t >> 6;
  const int quad = lane >> 4, l16 = lane & 15;
  const int m0 = blockIdx.y * 128, n0 = blockIdx.x * 128;
  const int wm = (wave >> 1) * 64, wn = (wave & 1) * 64;

  f32x4 acc[4][4];
#pragma unroll
  for (int i = 0; i < 4; i++)
#pragma unroll
    for (int j = 0; j < 4; j++) { acc[i][j][0]=0.f; acc[i][j][1]=0.f; acc[i][j][2]=0.f; acc[i][j][3]=0.f; }

  const int rr = t >> 2;
  const int cc = (t & 3) * 8;

#define QKV_STAGE(bufidx, k0_) do {                                               \
    char* a_ = smem + (bufidx) * 8192;                                            \
    char* b_ = smem + 16384 + (bufidx) * 8192;                                    \
    _Pragma("unroll")                                                             \
    for (int i_ = 0; i_ < 2; i_++) {                                              \
      load_lds16(X  + (uint64_t)(m0 + i_ * 64 + rr) * 1024 + (k0_) + cc,          \
                 a_ + i_ * 4096 + wave * 1024);                                   \
      load_lds16(W3 + (uint64_t)(n0 + i_ * 64 + rr) * 1024 + (k0_) + cc,          \
                 b_ + i_ * 4096 + wave * 1024);                                   \
    }                                                                             \
  } while (0)

  QKV_STAGE(0, 0);

  for (int k0 = 0; k0 < 1024; k0 += 32) {
    const int buf = (k0 >> 5) & 1;
    ASM_VMCNT0;
    ASM_BARRIER;
    if (k0 + 32 < 1024) QKV_STAGE(buf ^ 1, k0 + 32);
    char* As = smem + buf * 8192;
    char* Bs = smem + 16384 + buf * 8192;

    bf16x8 af[4], bfr[4];
#pragma unroll
    for (int i = 0; i < 4; i++) {
      af[i]  = *(const bf16x8*)(As + (wm + i * 16 + l16) * 64 + quad * 16);
      bfr[i] = *(const bf16x8*)(Bs + (wn + i * 16 + l16) * 64 + quad * 16);
    }
#pragma unroll
    for (int i = 0; i < 4; i++)
#pragma unroll
      for (int j = 0; j < 4; j++)
        acc[i][j] = __builtin_amdgcn_mfma_f32_16x16x32_bf16(af[i], bfr[j], acc[i][j], 0, 0, 0);
  }
#undef QKV_STAGE

  if (n0 < 2048) {
    unsigned short* dst = (n0 < 1024) ? Qr : Kr;
    float fr[4]; int dd[4], hh[4];
#pragma unroll
    for (int j = 0; j < 4; j++) {
      const int n = n0 + wn + j * 16 + l16;
      dd[j] = n & 63;
      hh[j] = (n & 1023) >> 6;
      fr[j] = __builtin_amdgcn_exp2f(-0.20762050594f * (float)(dd[j] & ~1)) * 0.15915494309f;
    }
    const float sgnodd = (l16 & 1) ? 1.f : -1.f;
#pragma unroll
    for (int i = 0; i < 4; i++) {
#pragma unroll
      for (int r = 0; r < 4; r++) {
        const int m = m0 + wm + i * 16 + quad * 4 + r;
        const int s = m & 2047, b = m >> 11;
        const float posf = (float)tp[m];
#pragma unroll
        for (int j = 0; j < 4; j++) {
          const float v = acc[i][j][r];
          const float p = __shfl_xor(v, 1);
          float rev = posf * fr[j];
          rev -= floorf(rev);
          float sn, cs;
          asm("v_sin_f32 %0, %1" : "=v"(sn) : "v"(rev));
          asm("v_cos_f32 %0, %1" : "=v"(cs) : "v"(rev));
          const float rv = fmaf(v, cs, p * sn * sgnodd);
          dst[((uint64_t)((b * NH + hh[j]) * SEQ + s)) * 64 + dd[j]] = f2bf(rv);
        }
      }
    }
  } else {
    // V -> Vt (b,h,d,s_permuted): 4 consecutive s (=j) share (quad_v, nb_v).
#pragma unroll
    for (int i = 0; i < 4; i++) {
      const int m = m0 + wm + i * 16 + quad * 4;
      const int s = m & 2047, b = m >> 11;
      const int sl = s & 63;
      const int qv = (sl >> 2) & 3, nv = sl >> 4;
      const int g = (s & ~63) + qv * 16 + (nv >> 1) * 8 + (nv & 1) * 4;
#pragma unroll
      for (int j = 0; j < 4; j++) {
        const int n = n0 - 2048 + wn + j * 16 + l16;
        const int h = n >> 6, d = n & 63;
        uint2 w;
        w.x = pk2(acc[i][j][0], acc[i][j][1]);
        w.y = pk2(acc[i][j][2], acc[i][j][3]);
        *(uint2*)(Vt + ((uint64_t)((b * NH + h) * 64 + d)) * SEQ + g) = w;
      }
    }
  }
}

// ---------------------------------------------------------------------------
// Output projection: C = At (4096x1024) @ wo^T, fp32 out. 128x128 tiles,
// grid (8,32) = 256 blocks (1/CU), XCD-GROUPED remap (R7) + 512 threads /
// 8 waves (R9: 2 waves/SIMD, kept).
// ---------------------------------------------------------------------------
__launch_bounds__(512, 2)
__global__ void gemm_ao(const unsigned short* __restrict__ A,
                        const unsigned short* __restrict__ B,
                        float* __restrict__ C) {
  __shared__ __align__(16) char smem[32768];

  const int t = threadIdx.x;
  const int lane = t & 63, wave = t >> 6;       // wave = 0..7
  const int quad = lane >> 4, l16 = lane & 15;
  const int id = blockIdx.y * 8 + blockIdx.x;   // linear dispatch id, 0..255
  const int k = id & 7;                         // XCD (1 block/CU round-robin)
  const int tt = id >> 3;                       // 0..31
  const int m0 = (k * 4 + (tt & 3)) * 128;      // XCD k: m-strips 4k..4k+3
  const int n0 = (tt >> 2) * 128;               // all 8 n-strips
  const int wm = (wave >> 2) * 64;              // 2 m-groups
  const int wn = (wave & 3) * 32;               // 4 n-groups

  f32x4 acc[4][2];
#pragma unroll
  for (int i = 0; i < 4; i++)
#pragma unroll
    for (int j = 0; j < 2; j++) { acc[i][j][0]=0.f; acc[i][j][1]=0.f; acc[i][j][2]=0.f; acc[i][j][3]=0.f; }

  const int rr = t >> 2;          // 0..127: full 128-row tile in one call
  const int cc = (t & 3) * 8;

#define AO_STAGE(bufidx, k0_) do {                                               \
    char* a_ = smem + (bufidx) * 8192;                                            \
    char* b_ = smem + 16384 + (bufidx) * 8192;                                    \
    load_lds16(A + (uint64_t)(m0 + rr) * 1024 + (k0_) + cc, a_ + wave * 1024);    \
    load_lds16(B + (uint64_t)(n0 + rr) * 1024 + (k0_) + cc, b_ + wave * 1024);    \
  } while (0)

  AO_STAGE(0, 0);

  for (int k0 = 0; k0 < 1024; k0 += 32) {
    const int buf = (k0 >> 5) & 1;
    ASM_VMCNT0;
    ASM_BARRIER;
    if (k0 + 32 < 1024) AO_STAGE(buf ^ 1, k0 + 32);
    char* As = smem + buf * 8192;
    char* Bs = smem + 16384 + buf * 8192;

    bf16x8 af[4], bfr[2];
#pragma unroll
    for (int i = 0; i < 4; i++)
      af[i]  = *(const bf16x8*)(As + (wm + i * 16 + l16) * 64 + quad * 16);
#pragma unroll
    for (int j = 0; j < 2; j++)
      bfr[j] = *(const bf16x8*)(Bs + (wn + j * 16 + l16) * 64 + quad * 16);
#pragma unroll
    for (int i = 0; i < 4; i++)
#pragma unroll
      for (int j = 0; j < 2; j++)
        acc[i][j] = __builtin_amdgcn_mfma_f32_16x16x32_bf16(af[i], bfr[j], acc[i][j], 0, 0, 0);
  }
#undef AO_STAGE

#pragma unroll
  for (int i = 0; i < 4; i++)
#pragma unroll
    for (int j = 0; j < 2; j++)
#pragma unroll
      for (int r = 0; r < 4; r++) {
        const int m = m0 + wm + i * 16 + quad * 4 + r;
        const int n = n0 + wn + j * 16 + l16;
        C[(uint64_t)m * DM + n] = acc[i][j][r];
      }
}

// ---------------------------------------------------------------------------
// Flash attention r19 (REVERT to the verified best: total 166.7us, flash ~38).
// 2x2 WAVE SPLIT (key-half x q-half), K+V both LDS-staged.
// R11/R12 closed the staging question: staging buys BOTH prefetch distance
// (R11: no staging -> +34us, L2-latency-bound) AND coalescing (R12: direct
// per-fragment V reads touch 64 lines/instr via 4KB row stride -> +11us).
// Exploration tree exhausted around this point: R1 vmcnt null, R2/R5 widening
// spills, R3 TLP +10%, R4/R8 balance null, R6 setprio -8%, R10 key-split
// -10% (kept), R11/R12 de-staging negative. Local optimum; frozen.
// ---------------------------------------------------------------------------
__launch_bounds__(256, 4)
__global__ void flash_attn(const unsigned short* __restrict__ Q,
                           const unsigned short* __restrict__ K,
                           const unsigned short* __restrict__ Vt,
                           unsigned short* __restrict__ Oa) {
  __shared__ __align__(16) char smem[32768];
  // K dbuf: 0 / 8192; V dbuf: 16384 / 24576; reduction reuses [0,16640)

  const int t = threadIdx.x;
  const int lane = t & 63, wid = t >> 6;     // wid = 0..3
  const int quad = lane >> 4, l16 = lane & 15;
  const int kw = wid & 1;                    // key-half owned by this wave
  const int qw = wid >> 1;                   // q-half owned by this wave
  const int u = blockIdx.x;
  const int m = u >> 5;                      // 0..31
  const int tq = (m < 16) ? (31 - m) : (m - 16);  // symmetric: per-CU sum 66
  const int bh = u & 31;
  const uint64_t base = (uint64_t)bh * (SEQ * 64);
  const int qb = tq * 64;
  const int ng = tq + 1;                     // K-tiles for this Q-tile
  const int b = bh >> 4, h = bh & 15;
  const int qlo = qb + qw * 32;              // wave's q range [qlo, qlo+32)

  // Q B-fragments for both 16-q subgroups (n=q=l16, k=d=kk*32+quad*8+j)
  bf16x8 qf[2][2];
  {
    const unsigned short* qp0 = Q + base + (uint64_t)(qlo + l16) * 64 + quad * 8;
    qf[0][0] = *(const bf16x8*)qp0;  qf[0][1] = *(const bf16x8*)(qp0 + 32);
    const unsigned short* qp1 = Q + base + (uint64_t)(qlo + 16 + l16) * 64 + quad * 8;
    qf[1][0] = *(const bf16x8*)qp1;  qf[1][1] = *(const bf16x8*)(qp1 + 32);
  }

  f32x4 o[2][4];                             // [qg][db], partial over wave's keys
#pragma unroll
  for (int qg = 0; qg < 2; qg++)
#pragma unroll
    for (int db = 0; db < 4; db++) { o[qg][db][0]=0.f; o[qg][db][1]=0.f; o[qg][db][2]=0.f; o[qg][db][3]=0.f; }
  float lI0 = 0.f, lI1 = 0.f;                // per-qg l partials

  // staging: 256 threads cover a 64-row x 128B tile in 2 calls/array.
  // LDS chunk c at row r holds global 16B-chunk c ^ (r&7).
  const int sr8 = lane >> 3;
  const int sc = ((lane & 7) ^ sr8) * 8;     // shorts
  const int swz = (l16 & 7);

#define STAGE(bufidx, kb_) do {                                                   \
    _Pragma("unroll")                                                             \
    for (int i_ = 0; i_ < 2; i_++) {                                              \
      const int r_ = wid * 16 + i_ * 8 + sr8;                                     \
      load_lds16(K  + base + (uint64_t)((kb_) + r_) * 64 + sc,                    \
                 smem + (bufidx) * 8192 + wid * 2048 + i_ * 1024);                \
      load_lds16(Vt + base + (uint64_t)r_ * SEQ + (kb_) + sc,                     \
                 smem + 16384 + (bufidx) * 8192 + wid * 2048 + i_ * 1024);        \
    }                                                                             \
  } while (0)

  STAGE(0, 0);

  const float c1 = 0.18033688011f;  // log2(e)/8

  for (int it = 0; it < ng; it++) {
    const int kb = it * 64;
    const int buf = it & 1;
    ASM_VMCNT0;     // stage(it) loads were issued a full iteration ago
    ASM_BARRIER;
    if (it + 1 < ng) STAGE(buf ^ 1, (it + 1) * 64);
    char* ks = smem + buf * 8192;
    char* vs = smem + 16384 + buf * 8192;

    // wave's valid 16-key groups among {2kw, 2kw+1} relative to kb
    int nv = ((qlo + 31 - kb) >> 4) + 1 - 2 * kw;
    nv = nv > 2 ? 2 : (nv < 0 ? 0 : nv);
    const bool diag = (kb + kw * 32 + 31) > qlo;   // wave-uniform

    if (nv > 0) {
      // S^T = K Q^T : key = kb + (2kw+nbp)*16 + quad*4 + r, q (per qg) = l16
      f32x4 sf0[2], sf1[2];    // [nbp] for qg=0 / qg=1
      float ls0 = 0.f, ls1 = 0.f;
#pragma unroll
      for (int nbp = 0; nbp < 2; nbp++) {
        if (nbp < nv) {
          f32x4 s0; s0[0]=0.f; s0[1]=0.f; s0[2]=0.f; s0[3]=0.f;
          f32x4 s1; s1[0]=0.f; s1[1]=0.f; s1[2]=0.f; s1[3]=0.f;
#pragma unroll
          for (int kk = 0; kk < 2; kk++) {
            bf16x8 kfr = *(const bf16x8*)(ks + ((2 * kw + nbp) * 16 + l16) * 128 +
                                          (((kk * 4 + quad) ^ swz) * 16));
            s0 = __builtin_amdgcn_mfma_f32_16x16x32_bf16(kfr, qf[0][kk], s0, 0, 0, 0);
            s1 = __builtin_amdgcn_mfma_f32_16x16x32_bf16(kfr, qf[1][kk], s1, 0, 0, 0);
          }
          if (diag) {
#pragma unroll
            for (int r = 0; r < 4; r++) {
              const int key = kb + (2 * kw + nbp) * 16 + quad * 4 + r;
              const float p0 = (key <= qlo + l16)      ? __builtin_amdgcn_exp2f(s0[r] * c1) : 0.f;
              const float p1 = (key <= qlo + 16 + l16) ? __builtin_amdgcn_exp2f(s1[r] * c1) : 0.f;
              sf0[nbp][r] = p0;  ls0 += p0;
              sf1[nbp][r] = p1;  ls1 += p1;
            }
          } else {
#pragma unroll
            for (int r = 0; r < 4; r++) {
              const float p0 = __builtin_amdgcn_exp2f(s0[r] * c1);
              const float p1 = __builtin_amdgcn_exp2f(s1[r] * c1);
              sf0[nbp][r] = p0;  ls0 += p0;
              sf1[nbp][r] = p1;  ls1 += p1;
            }
          }
        }
      }
      lI0 += ls0;  lI1 += ls1;

      // PV: V-frag pair for THIS wave's nb pair (= kw) in ONE b128.
      union { uint2 u; s16x4 h; } a0, b0, a1, b1;
      a0.u.x = pk2(sf0[0][0], sf0[0][1]);  a0.u.y = pk2(sf0[0][2], sf0[0][3]);
      b0.u.x = pk2(sf1[0][0], sf1[0][1]);  b0.u.y = pk2(sf1[0][2], sf1[0][3]);
      const bool hi = (nv > 1);
      if (hi) {
        a1.u.x = pk2(sf0[1][0], sf0[1][1]);  a1.u.y = pk2(sf0[1][2], sf0[1][3]);
        b1.u.x = pk2(sf1[1][0], sf1[1][1]);  b1.u.y = pk2(sf1[1][2], sf1[1][3]);
      }
#pragma unroll
      for (int db = 0; db < 4; db++) {
        s16x8 vv = *(const s16x8*)(vs + (db * 16 + l16) * 128 +
                                   (((quad * 2 + kw) ^ swz) * 16));
        s16x4 vlo = __builtin_shufflevector(vv, vv, 0, 1, 2, 3);
        o[0][db] = __builtin_amdgcn_mfma_f32_16x16x16bf16_1k(vlo, a0.h, o[0][db], 0, 0, 0);
        o[1][db] = __builtin_amdgcn_mfma_f32_16x16x16bf16_1k(vlo, b0.h, o[1][db], 0, 0, 0);
        if (hi) {
          s16x4 vhi = __builtin_shufflevector(vv, vv, 4, 5, 6, 7);
          o[0][db] = __builtin_amdgcn_mfma_f32_16x16x16bf16_1k(vhi, a1.h, o[0][db], 0, 0, 0);
          o[1][db] = __builtin_amdgcn_mfma_f32_16x16x16bf16_1k(vhi, b1.h, o[1][db], 0, 0, 0);
        }
      }
    }
  }
#undef STAGE

  // reduce l across quads (per qg): butterfly leaves full wave-partial in all lanes
  float lr0 = lI0;  lr0 += __shfl_xor(lr0, 16);  lr0 += __shfl_xor(lr0, 32);
  float lr1 = lI1;  lr1 += __shfl_xor(lr1, 16);  lr1 += __shfl_xor(lr1, 32);

  // cross-kw reduction: kw=1 dumps partials to LDS, kw=0 adds + finalizes.
  ASM_LGKM0;        // all my LDS reads retired before anyone overwrites smem
  ASM_BARRIER;
  if (kw) {
    char* pbase = smem + qw * 8192;
#pragma unroll
    for (int qg = 0; qg < 2; qg++)
#pragma unroll
      for (int db = 0; db < 4; db++)
        *(f32x4*)(pbase + (qg * 4 + db) * 1024 + quad * 256 + l16 * 16) = o[qg][db];
    if (quad == 0) {
      *(float*)(smem + 16384 + qw * 128 + l16 * 4) = lr0;
      *(float*)(smem + 16384 + qw * 128 + 64 + l16 * 4) = lr1;
    }
  }
  ASM_LGKM0;
  ASM_BARRIER;
  if (!kw) {
    char* pbase = smem + qw * 8192;
#pragma unroll
    for (int qg = 0; qg < 2; qg++) {
      const float lpart = *(const float*)(smem + 16384 + qw * 128 + qg * 64 + l16 * 4);
      const float invl = 1.0f / ((qg ? lr1 : lr0) + lpart);
      const int qrow = qlo + qg * 16 + l16;
      unsigned short* orow = Oa + ((uint64_t)(b * SEQ + qrow)) * DM + h * 64 + quad * 4;
#pragma unroll
      for (int db = 0; db < 4; db++) {
        const f32x4 p = *(const f32x4*)(pbase + (qg * 4 + db) * 1024 + quad * 256 + l16 * 16);
        uint2 w;
        w.x = pk2((o[qg][db][0] + p[0]) * invl, (o[qg][db][1] + p[1]) * invl);
        w.y = pk2((o[qg][db][2] + p[2]) * invl, (o[qg][db][3] + p[3]) * invl);
        *(uint2*)(orow + db * 16) = w;
      }
    }
  }
}

extern "C" void kernel_launch(void* const* d_in, const int* in_sizes, int n_in,
                              void* d_out, int out_size, void* d_ws, size_t ws_size,
                              hipStream_t stream) {
  const float* x  = (const float*)d_in[0];
  const int* tp   = (const int*)d_in[1];
  const float* wq = (const float*)d_in[2];
  const float* wk = (const float*)d_in[3];
  const float* wv = (const float*)d_in[4];
  const float* wo = (const float*)d_in[5];
  float* out = (float*)d_out;

  unsigned short* ws = (unsigned short*)d_ws;
  unsigned short* xb  = ws;                   // (b,s,dm) bf16        8 MB
  unsigned short* w3b = ws + 4194304;         // [wq;wk;wv] 3072x1024 6 MB
  unsigned short* wob = ws + 7340032;         // 2 MB
  unsigned short* Qr  = ws + 8388608;         // (b,h,s,64)  8 MB
  unsigned short* Kr  = ws + 12582912;        // (b,h,s,64)  8 MB
  unsigned short* Vt  = ws + 16777216;        // (b,h,64,s-perm)  8 MB
  unsigned short* At  = ws + 20971520;        // (b,s,h*64)  8 MB

  cvt_all<<<8192, 256, 0, stream>>>(x, wq, wk, wv, wo, ws);
  gemm_qkv<<<dim3(24, 32), 256, 0, stream>>>(xb, w3b, Qr, Kr, Vt, tp);
  flash_attn<<<1024, 256, 0, stream>>>(Qr, Kr, Vt, At);
  gemm_ao<<<dim3(8, 32), 512, 0, stream>>>(At, wob, out);
}